// Round 1
// baseline (767.614 us; speedup 1.0000x reference)
//
#include <hip/hip_runtime.h>
#include <hip/hip_bf16.h>

// Problem constants
#define B_   2
#define C_   64
#define H_   96
#define W_   192
#define D_   48
#define G_   8
#define OUT_ 32
#define HW_  (H_ * W_)   // 18432

// Padded f16 correlation volume: (B, DP, HP, WP, 8) halfs, halo = 4
#define DP_ 56
#define HP_ 104
#define WP_ 200
#define PLANE_ (HP_ * WP_ * 8)          // halfs per d-plane = 166400
#define BASEH_HALFS (B_ * DP_ * PLANE_) // 18,636,800 halfs = 37.27 MB

// Workspace layout (float offsets)
#define OFF_FLN   0                        // (B,G,H,W,8) fp32       2,359,296
#define OFF_FRN   2359296                  // (B,G,H,W,8) fp32       2,359,296
#define OFF_BASEH 4718592                  // f16 padded volume      9,318,400 float-slots
#define OFF_SW    14036992                 // (3,B*HW) fp32            110,592
#define OFF_BPACK 14147584                 // f16 B-frags               10,752 float-slots
#define OFF_WP1T  14158336                 // (65,9,32) fp32            18,720

typedef _Float16 f16x8  __attribute__((ext_vector_type(8)));
typedef float    f32x4  __attribute__((ext_vector_type(4)));
typedef float    f32x16 __attribute__((ext_vector_type(16)));

// ---------------------------------------------------------------------------
// Kernel 0: weight prep for 32x32x16 MFMA.
//  bpack[((k*14+c)*64+lane)*8+j] = f16( V_k[tap(c,hf)][gi=j][n=lane&31] )
//  hf = lane>>5. Chunk->tap mapping (must match fused kernel's addressing):
//   c in [0,9):  kd = hf? +1 : -1 ; kh = c/3-1 ; kw = c%3-1
//   c in [9,12): kd = 0 ; kh = hf? +1 : -1 ; kw = (c-9)-1
//   c == 12:     kd = 0 ; kh = 0 ; kw = hf? +1 : -1
//   c == 13:     hf==0 -> center (0,0,0) ; hf==1 -> zero pad
//  V_k[tap][gi][n] = sum_g w_final[n*8+g] * w_k[(g*8+gi)*27+tap]
//  part B: wp1T[ic][t][oc] = w_pred1[oc][ic][t]
// ---------------------------------------------------------------------------
__global__ void wtrans_kernel(const float* __restrict__ w_s,
                              const float* __restrict__ w_m,
                              const float* __restrict__ w_l,
                              const float* __restrict__ w_final,
                              const float* __restrict__ w_pred1,
                              _Float16* __restrict__ bpack,
                              float* __restrict__ wp1T) {
    int i = blockIdx.x * 256 + threadIdx.x;
    if (i < 21504) {
        int j = i & 7;                 // gi
        int lane = (i >> 3) & 63;
        int kc = i >> 9;               // 0..41
        int c = kc % 14, k = kc / 14;
        int hf = lane >> 5, n = lane & 31;
        int kd = 0, kh = 0, kw = 0; bool valid = true;
        if (c < 9)        { kd = hf ? 1 : -1; kh = c / 3 - 1; kw = c % 3 - 1; }
        else if (c < 12)  { kd = 0; kh = hf ? 1 : -1; kw = (c - 9) - 1; }
        else if (c == 12) { kd = 0; kh = 0; kw = hf ? 1 : -1; }
        else              { valid = (hf == 0); }
        float val = 0.f;
        if (valid) {
            int tap = (kd + 1) * 9 + (kh + 1) * 3 + (kw + 1);
            const float* wsel = (k == 0) ? w_s : (k == 1) ? w_m : w_l;
            #pragma unroll
            for (int g = 0; g < 8; ++g)
                val += w_final[n * 8 + g] * wsel[(g * 8 + j) * 27 + tap];
        }
        bpack[i] = (_Float16)val;
    } else if (i < 21504 + 18720) {
        int j = i - 21504;
        int oc = j & 31; int it = j >> 5; int ic = it / 9; int t = it - ic * 9;
        wp1T[j] = w_pred1[(oc * 65 + ic) * 9 + t];
    }
}

// ---------------------------------------------------------------------------
// Kernel 1: group-L2-normalize + transpose to channel-last (B,G,H,W,8)
// ---------------------------------------------------------------------------
__global__ __launch_bounds__(256) void norm_kernel(const float* __restrict__ feat_l,
                                                   const float* __restrict__ feat_r,
                                                   float* __restrict__ fln,
                                                   float* __restrict__ frn) {
    int hw = blockIdx.x * 256 + threadIdx.x;
    int bg = blockIdx.y;
    const float* src = blockIdx.z ? feat_r : feat_l;
    float*       dst = blockIdx.z ? frn    : fln;
    float v[8]; float s = 0.f;
    #pragma unroll
    for (int c = 0; c < 8; ++c) {
        v[c] = src[(bg * 8 + c) * HW_ + hw];
        s += v[c] * v[c];
    }
    float inv = 1.0f / fmaxf(sqrtf(s), 1e-12f);
    #pragma unroll
    for (int c = 0; c < 8; ++c) dst[((long)bg * HW_ + hw) * 8 + c] = v[c] * inv;
}

// ---------------------------------------------------------------------------
// Kernel 2: correlation volume -> padded f16 channel-last volume
// ---------------------------------------------------------------------------
__global__ __launch_bounds__(256) void corr_kernel(const float* __restrict__ fln,
                                                   const float* __restrict__ frn,
                                                   _Float16* __restrict__ baseh) {
    int tid = threadIdx.x;
    int g = tid & 7, wi = tid >> 3;
    int w = blockIdx.x * 32 + wi;
    int h = blockIdx.y;
    int b = blockIdx.z;
    const float* flp  = fln + (size_t)((((b * G_ + g) * H_ + h) * W_ + w)) * 8;
    const float* frow = frn + (size_t)((((b * G_ + g) * H_ + h) * W_)) * 8;
    f32x4 a0 = *(const f32x4*)(flp);
    f32x4 a1 = *(const f32x4*)(flp + 4);
    const float inv = 0.35355339059327373f;  // 1/sqrt(8)
    _Float16* dst = baseh + (size_t)((b * DP_ + 4) * HP_ + 4 + h) * WP_ * 8 + (size_t)(4 + w) * 8 + g;
    for (int d = 0; d < D_; ++d) {
        int wd = w - d;
        float acc = 0.f;
        if (wd >= 0) {
            f32x4 b0 = *(const f32x4*)(frow + wd * 8);
            f32x4 b1 = *(const f32x4*)(frow + wd * 8 + 4);
            acc = a0[0]*b0[0] + a0[1]*b0[1] + a0[2]*b0[2] + a0[3]*b0[3]
                + a1[0]*b1[0] + a1[1]*b1[1] + a1[2]*b1[2] + a1[3]*b1[3];
            acc *= inv;
        }
        dst[(size_t)d * PLANE_] = (_Float16)acc;
    }
}

// ---------------------------------------------------------------------------
// Kernel 3: 2D conv(65->32,3x3)+BN+relu+1x1(32->3)+softmax -> 3 planes swp[k]
//  ic-split 4 ways (17/17/17/14 channels), LDS reduce, 64 px per block.
//  Quadruples wave count (576 -> 2304 waves) for latency hiding.
// ---------------------------------------------------------------------------
__global__ __launch_bounds__(256) void pred_kernel(const float* __restrict__ feat_l,
                                                   const float* __restrict__ edge,
                                                   const float* __restrict__ wp1T,
                                                   const float* __restrict__ gamma,
                                                   const float* __restrict__ beta,
                                                   const float* __restrict__ mean,
                                                   const float* __restrict__ var,
                                                   const float* __restrict__ w2,
                                                   const float* __restrict__ b2,
                                                   const float* __restrict__ temp,
                                                   float* __restrict__ swp) {
    __shared__ float red[3][64][33];   // pad 33: conflict-free (bank = px+oc)
    int tid = threadIdx.x;
    int px  = tid & 63;
    int grp = tid >> 6;                // 0..3 ic-groups
    int pid = blockIdx.x * 64 + px;    // 0..36863
    int b = pid / HW_; int hw = pid - b * HW_;
    int h = hw / W_;   int w = hw - h * W_;

    int ic0 = grp * 17;
    int ic1 = (grp == 3) ? 65 : ic0 + 17;

    float acc[32];
    #pragma unroll
    for (int i = 0; i < 32; ++i) acc[i] = 0.f;

    for (int ic = ic0; ic < ic1; ++ic) {
        const float* src = (ic < 64) ? (feat_l + (size_t)(b * 64 + ic) * HW_)
                                     : (edge + (size_t)b * HW_);
        float v[9];
        #pragma unroll
        for (int ky = 0; ky < 3; ++ky) {
            int y = h + ky - 1;
            #pragma unroll
            for (int kx = 0; kx < 3; ++kx) {
                int x = w + kx - 1;
                bool ok = (y >= 0) && (y < H_) && (x >= 0) && (x < W_);
                v[ky * 3 + kx] = ok ? src[y * W_ + x] : 0.f;
            }
        }
        #pragma unroll
        for (int t = 0; t < 9; ++t) {
            const float* wrow = wp1T + (ic * 9 + t) * 32;
            float vv = v[t];
            #pragma unroll
            for (int oc = 0; oc < 32; ++oc) acc[oc] = fmaf(vv, wrow[oc], acc[oc]);
        }
    }

    if (grp) {
        #pragma unroll
        for (int oc = 0; oc < 32; ++oc) red[grp - 1][px][oc] = acc[oc];
    }
    __syncthreads();
    if (grp == 0) {
        #pragma unroll
        for (int oc = 0; oc < 32; ++oc)
            acc[oc] += red[0][px][oc] + red[1][px][oc] + red[2][px][oc];

        float l0 = b2[0], l1 = b2[1], l2 = b2[2];
        #pragma unroll
        for (int oc = 0; oc < 32; ++oc) {
            float sc = gamma[oc] / sqrtf(var[oc] + 1e-5f);
            float xb = (acc[oc] - mean[oc]) * sc + beta[oc];
            float r = fmaxf(xb, 0.f);
            l0 = fmaf(w2[0 * 32 + oc], r, l0);
            l1 = fmaf(w2[1 * 32 + oc], r, l1);
            l2 = fmaf(w2[2 * 32 + oc], r, l2);
        }
        float t = fmaxf(temp[0], 0.1f);
        float it = 1.0f / t;
        l0 *= it; l1 *= it; l2 *= it;
        float m = fmaxf(l0, fmaxf(l1, l2));
        float e0 = __expf(l0 - m), e1 = __expf(l1 - m), e2 = __expf(l2 - m);
        float is = 1.0f / (e0 + e1 + e2);
        swp[0 * (B_ * HW_) + pid] = e0 * is;
        swp[1 * (B_ * HW_) + pid] = e1 * is;
        swp[2 * (B_ * HW_) + pid] = e2 * is;
    }
}

// ---------------------------------------------------------------------------
// Kernel 4: MFMA 32x32x16 fused conv.
//  Wave = 32 consecutive w at fixed (b,h), sweeping 12 d values (wave = d-chunk).
//  A[m=lane&31][kk=(lane>>5)*8+j]: lane loads 8 gi-halfs of tap T(c,hf) at
//  row w0+m — fed DIRECTLY into MFMA (no VALU on the load->MFMA path).
//  Softmax weights applied at the EPILOGUE: sw_k depends only on the output
//  row r = (reg&3)+8*(reg>>2)+4*hf (a w-offset), so 3 per-scale accumulator
//  chains (interleaved, dep-distance 3 >= MFMA latency) are scaled by
//  f32x4 sw loads (L1-hot, 1.5KB per tile) after accumulation.
//  D: col = lane&31 = o, row = (reg&3)+8*(reg>>2)+4*hf = w-offset.
// block 256 = 4 waves = 4 d-chunks; grid = (6 wtiles, 96 h, B)
// __launch_bounds__(256,4): pin VGPR <= 128 so 4 waves/SIMD are resident.
// ---------------------------------------------------------------------------
__global__ __launch_bounds__(256, 4) void fusedconv_mfma32(
        const _Float16* __restrict__ baseh,
        const float* __restrict__ swp,
        const _Float16* __restrict__ bpack,
        const float* __restrict__ bf,
        float* __restrict__ out) {
    int tid = threadIdx.x;
    int wave = tid >> 6, lane = tid & 63;
    int m = lane & 31, hf = lane >> 5;
    int w0 = blockIdx.x * 32;
    int h  = blockIdx.y;
    int b  = blockIdx.z;
    int d0 = wave * 12;

    // half-wave address deltas per (scale, class), bytes
    int hdv[3][4];
    #pragma unroll
    for (int k = 0; k < 3; ++k) {
        int dil = 1 << k;
        hdv[k][0] = hf * (2 * dil * HP_ * WP_ * 8 * 2);
        hdv[k][1] = hf * (2 * dil * WP_ * 8 * 2);
        hdv[k][2] = hf * (2 * dil * 8 * 2);
        hdv[k][3] = 0;
    }

    const char* bb = (const char*)baseh;
    char*       ob = (char*)out;

    // byte offset of interior origin (d0-plane, h, w0+m)
    unsigned pm = (unsigned)(((((b * DP_ + 4 + d0) * HP_ + 4 + h) * WP_ + 4 + w0 + m) * 8) * 2);
    float bias = bf[m];   // o = lane&31
    unsigned outoff = (unsigned)((((b * OUT_ + m) * D_ + d0) * HW_ + h * W_ + w0 + 4 * hf) * 4);

    const float* swb = swp + b * HW_ + h * W_ + w0 + 4 * hf;

    for (int d = 0; d < 12; ++d) {
        f32x16 a0, a1, a2;
        #pragma unroll
        for (int i = 0; i < 16; ++i) { a0[i] = 0.f; a1[i] = 0.f; a2[i] = 0.f; }
        #pragma unroll
        for (int c = 0; c < 14; ++c) {
            #pragma unroll
            for (int k = 0; k < 3; ++k) {
                int dil = 1 << k;
                int coff, cls;
                if (c < 9)        { coff = ((-dil * HP_ + (c / 3 - 1) * dil) * WP_ * 8 + (c % 3 - 1) * dil * 8) * 2; cls = 0; }
                else if (c < 12)  { coff = ((-dil) * WP_ * 8 + ((c - 9) - 1) * dil * 8) * 2;                          cls = 1; }
                else if (c == 12) { coff = -dil * 16;                                                                  cls = 2; }
                else              { coff = 0;                                                                          cls = 3; }
                unsigned a = pm + (unsigned)(hdv[k][cls] + coff);
                f16x8 av = *(const f16x8*)(bb + a);
                f16x8 Bv = *(const f16x8*)(bpack + ((k * 14 + c) * 64 + lane) * 8);
                if (k == 0)      a0 = __builtin_amdgcn_mfma_f32_32x32x16_f16(av, Bv, a0, 0, 0, 0);
                else if (k == 1) a1 = __builtin_amdgcn_mfma_f32_32x32x16_f16(av, Bv, a1, 0, 0, 0);
                else             a2 = __builtin_amdgcn_mfma_f32_32x32x16_f16(av, Bv, a2, 0, 0, 0);
            }
        }
        // epilogue: out[row r=8q+4hf+i, col o=m] = sum_k sw_k[w0+r]*acc_k + bias
        #pragma unroll
        for (int q = 0; q < 4; ++q) {
            f32x4 s0 = *(const f32x4*)(swb + 0 * (B_ * HW_) + 8 * q);
            f32x4 s1 = *(const f32x4*)(swb + 1 * (B_ * HW_) + 8 * q);
            f32x4 s2 = *(const f32x4*)(swb + 2 * (B_ * HW_) + 8 * q);
            f32x4 v;
            #pragma unroll
            for (int i = 0; i < 4; ++i)
                v[i] = a0[4 * q + i] * s0[i] + a1[4 * q + i] * s1[i]
                     + a2[4 * q + i] * s2[i] + bias;
            *(f32x4*)(ob + outoff + q * 32) = v;   // rows 8q+4hf..+3, o = m
        }
        pm += PLANE_ * 2;
        outoff += HW_ * 4;
    }
}

// ---------------------------------------------------------------------------
extern "C" void kernel_launch(void* const* d_in, const int* in_sizes, int n_in,
                              void* d_out, int out_size, void* d_ws, size_t ws_size,
                              hipStream_t stream) {
    const float* feat_l   = (const float*)d_in[0];
    const float* feat_r   = (const float*)d_in[1];
    const float* edge     = (const float*)d_in[2];
    const float* w_pred1  = (const float*)d_in[3];
    const float* bn_gamma = (const float*)d_in[4];
    const float* bn_beta  = (const float*)d_in[5];
    const float* bn_mean  = (const float*)d_in[6];
    const float* bn_var   = (const float*)d_in[7];
    const float* w_pred2  = (const float*)d_in[8];
    const float* b_pred2  = (const float*)d_in[9];
    const float* temp     = (const float*)d_in[10];
    const float* w_s      = (const float*)d_in[11];
    const float* w_m      = (const float*)d_in[12];
    const float* w_l      = (const float*)d_in[13];
    const float* w_final  = (const float*)d_in[14];
    const float* b_final  = (const float*)d_in[15];
    float* out = (float*)d_out;

    float* ws = (float*)d_ws;
    float*     fln   = ws + OFF_FLN;
    float*     frn   = ws + OFF_FRN;
    _Float16*  baseh = (_Float16*)(ws + OFF_BASEH);
    float*     swp   = ws + OFF_SW;
    _Float16*  bpack = (_Float16*)(ws + OFF_BPACK);
    float*     wp1T  = ws + OFF_WP1T;

    // 0: weight prep
    wtrans_kernel<<<dim3(158), 256, 0, stream>>>(w_s, w_m, w_l, w_final, w_pred1, bpack, wp1T);
    // zero the padded volume (halo must be 0; ws is poisoned each launch)
    hipMemsetAsync(baseh, 0, (size_t)BASEH_HALFS * sizeof(_Float16), stream);
    // 1: normalize
    norm_kernel<<<dim3(HW_ / 256, B_ * G_, 2), 256, 0, stream>>>(feat_l, feat_r, fln, frn);
    // 2: correlation volume -> padded f16
    corr_kernel<<<dim3(W_ / 32, H_, B_), 256, 0, stream>>>(fln, frn, baseh);
    // 3: pred path -> softmax planes (ic-split x4, LDS reduce)
    pred_kernel<<<dim3(B_ * HW_ / 64), 256, 0, stream>>>(feat_l, edge, wp1T, bn_gamma,
                                                         bn_beta, bn_mean, bn_var,
                                                         w_pred2, b_pred2, temp, swp);
    // 4: MFMA 32x32 fused conv (4 d-chunks per block, sw folded at epilogue)
    fusedconv_mfma32<<<dim3(W_ / 32, H_, B_), 256, 0, stream>>>(baseh, swp, bpack, b_final, out);
}

// Round 2
// 628.910 us; speedup vs baseline: 1.2205x; 1.2205x over previous
//
#include <hip/hip_runtime.h>
#include <hip/hip_bf16.h>

// Problem constants
#define B_   2
#define C_   64
#define H_   96
#define W_   192
#define D_   48
#define G_   8
#define OUT_ 32
#define HW_  (H_ * W_)   // 18432

// Padded f16 correlation volume: (B, DP, HP, WP, 8) halfs, halo = 4
#define DP_ 56
#define HP_ 104
#define WP_ 200
#define PLANE_ (HP_ * WP_ * 8)          // halfs per d-plane = 166400
#define BASEH_HALFS (B_ * DP_ * PLANE_) // 18,636,800 halfs = 37.27 MB

// Workspace layout (float offsets)
#define OFF_FLN   0                        // (B,G,H,W,8) fp32       2,359,296
#define OFF_FRN   2359296                  // (B,G,H,W,8) fp32       2,359,296
#define OFF_BASEH 4718592                  // f16 padded volume      9,318,400 float-slots
#define OFF_SW    14036992                 // (3,B*HW) fp32            110,592
#define OFF_BPACK 14147584                 // f16 B-frags               10,752 float-slots
#define OFF_WP1T  14158336                 // (65,9,32) fp32            18,720

typedef _Float16 f16x8  __attribute__((ext_vector_type(8)));
typedef float    f32x4  __attribute__((ext_vector_type(4)));
typedef float    f32x16 __attribute__((ext_vector_type(16)));

// ---------------------------------------------------------------------------
// Kernel 0: weight prep for 32x32x16 MFMA.
//  bpack[((k*14+c)*64+lane)*8+j] = f16( V_k[tap(c,hf)][gi=j][n=lane&31] )
//  hf = lane>>5. Chunk->tap mapping (must match fused kernel's addressing):
//   c in [0,9):  kd = hf? +1 : -1 ; kh = c/3-1 ; kw = c%3-1
//   c in [9,12): kd = 0 ; kh = hf? +1 : -1 ; kw = (c-9)-1
//   c == 12:     kd = 0 ; kh = 0 ; kw = hf? +1 : -1
//   c == 13:     hf==0 -> center (0,0,0) ; hf==1 -> zero pad
//  V_k[tap][gi][n] = sum_g w_final[n*8+g] * w_k[(g*8+gi)*27+tap]
//  part B: wp1T[ic][t][oc] = w_pred1[oc][ic][t]
// ---------------------------------------------------------------------------
__global__ void wtrans_kernel(const float* __restrict__ w_s,
                              const float* __restrict__ w_m,
                              const float* __restrict__ w_l,
                              const float* __restrict__ w_final,
                              const float* __restrict__ w_pred1,
                              _Float16* __restrict__ bpack,
                              float* __restrict__ wp1T) {
    int i = blockIdx.x * 256 + threadIdx.x;
    if (i < 21504) {
        int j = i & 7;                 // gi
        int lane = (i >> 3) & 63;
        int kc = i >> 9;               // 0..41
        int c = kc % 14, k = kc / 14;
        int hf = lane >> 5, n = lane & 31;
        int kd = 0, kh = 0, kw = 0; bool valid = true;
        if (c < 9)        { kd = hf ? 1 : -1; kh = c / 3 - 1; kw = c % 3 - 1; }
        else if (c < 12)  { kd = 0; kh = hf ? 1 : -1; kw = (c - 9) - 1; }
        else if (c == 12) { kd = 0; kh = 0; kw = hf ? 1 : -1; }
        else              { valid = (hf == 0); }
        float val = 0.f;
        if (valid) {
            int tap = (kd + 1) * 9 + (kh + 1) * 3 + (kw + 1);
            const float* wsel = (k == 0) ? w_s : (k == 1) ? w_m : w_l;
            #pragma unroll
            for (int g = 0; g < 8; ++g)
                val += w_final[n * 8 + g] * wsel[(g * 8 + j) * 27 + tap];
        }
        bpack[i] = (_Float16)val;
    } else if (i < 21504 + 18720) {
        int j = i - 21504;
        int oc = j & 31; int it = j >> 5; int ic = it / 9; int t = it - ic * 9;
        wp1T[j] = w_pred1[(oc * 65 + ic) * 9 + t];
    }
}

// ---------------------------------------------------------------------------
// Kernel 1: group-L2-normalize + transpose to channel-last (B,G,H,W,8)
// ---------------------------------------------------------------------------
__global__ __launch_bounds__(256) void norm_kernel(const float* __restrict__ feat_l,
                                                   const float* __restrict__ feat_r,
                                                   float* __restrict__ fln,
                                                   float* __restrict__ frn) {
    int hw = blockIdx.x * 256 + threadIdx.x;
    int bg = blockIdx.y;
    const float* src = blockIdx.z ? feat_r : feat_l;
    float*       dst = blockIdx.z ? frn    : fln;
    float v[8]; float s = 0.f;
    #pragma unroll
    for (int c = 0; c < 8; ++c) {
        v[c] = src[(bg * 8 + c) * HW_ + hw];
        s += v[c] * v[c];
    }
    float inv = 1.0f / fmaxf(sqrtf(s), 1e-12f);
    #pragma unroll
    for (int c = 0; c < 8; ++c) dst[((long)bg * HW_ + hw) * 8 + c] = v[c] * inv;
}

// ---------------------------------------------------------------------------
// Kernel 2: correlation volume -> padded f16 channel-last volume
// ---------------------------------------------------------------------------
__global__ __launch_bounds__(256) void corr_kernel(const float* __restrict__ fln,
                                                   const float* __restrict__ frn,
                                                   _Float16* __restrict__ baseh) {
    int tid = threadIdx.x;
    int g = tid & 7, wi = tid >> 3;
    int w = blockIdx.x * 32 + wi;
    int h = blockIdx.y;
    int b = blockIdx.z;
    const float* flp  = fln + (size_t)((((b * G_ + g) * H_ + h) * W_ + w)) * 8;
    const float* frow = frn + (size_t)((((b * G_ + g) * H_ + h) * W_)) * 8;
    f32x4 a0 = *(const f32x4*)(flp);
    f32x4 a1 = *(const f32x4*)(flp + 4);
    const float inv = 0.35355339059327373f;  // 1/sqrt(8)
    _Float16* dst = baseh + (size_t)((b * DP_ + 4) * HP_ + 4 + h) * WP_ * 8 + (size_t)(4 + w) * 8 + g;
    for (int d = 0; d < D_; ++d) {
        int wd = w - d;
        float acc = 0.f;
        if (wd >= 0) {
            f32x4 b0 = *(const f32x4*)(frow + wd * 8);
            f32x4 b1 = *(const f32x4*)(frow + wd * 8 + 4);
            acc = a0[0]*b0[0] + a0[1]*b0[1] + a0[2]*b0[2] + a0[3]*b0[3]
                + a1[0]*b1[0] + a1[1]*b1[1] + a1[2]*b1[2] + a1[3]*b1[3];
            acc *= inv;
        }
        dst[(size_t)d * PLANE_] = (_Float16)acc;
    }
}

// ---------------------------------------------------------------------------
// Kernel 3: 2D conv(65->32,3x3)+BN+relu+1x1(32->3)+softmax -> 3 planes swp[k]
// (Round-0 form: one pixel per thread; LDS-split variant was unproven)
// ---------------------------------------------------------------------------
__global__ __launch_bounds__(256) void pred_kernel(const float* __restrict__ feat_l,
                                                   const float* __restrict__ edge,
                                                   const float* __restrict__ wp1T,
                                                   const float* __restrict__ gamma,
                                                   const float* __restrict__ beta,
                                                   const float* __restrict__ mean,
                                                   const float* __restrict__ var,
                                                   const float* __restrict__ w2,
                                                   const float* __restrict__ b2,
                                                   const float* __restrict__ temp,
                                                   float* __restrict__ swp) {
    int pid = blockIdx.x * 256 + threadIdx.x;   // 0..36863
    int b = pid / HW_; int hw = pid - b * HW_;
    int h = hw / W_;   int w = hw - h * W_;

    float acc[32];
    #pragma unroll
    for (int i = 0; i < 32; ++i) acc[i] = 0.f;

    for (int ic = 0; ic < 65; ++ic) {
        const float* src = (ic < 64) ? (feat_l + (size_t)(b * 64 + ic) * HW_)
                                     : (edge + (size_t)b * HW_);
        float v[9];
        #pragma unroll
        for (int ky = 0; ky < 3; ++ky) {
            int y = h + ky - 1;
            #pragma unroll
            for (int kx = 0; kx < 3; ++kx) {
                int x = w + kx - 1;
                bool ok = (y >= 0) && (y < H_) && (x >= 0) && (x < W_);
                v[ky * 3 + kx] = ok ? src[y * W_ + x] : 0.f;
            }
        }
        #pragma unroll
        for (int t = 0; t < 9; ++t) {
            const float* wrow = wp1T + (ic * 9 + t) * 32;
            float vv = v[t];
            #pragma unroll
            for (int oc = 0; oc < 32; ++oc) acc[oc] = fmaf(vv, wrow[oc], acc[oc]);
        }
    }

    float l0 = b2[0], l1 = b2[1], l2 = b2[2];
    #pragma unroll
    for (int oc = 0; oc < 32; ++oc) {
        float sc = gamma[oc] / sqrtf(var[oc] + 1e-5f);
        float xb = (acc[oc] - mean[oc]) * sc + beta[oc];
        float r = fmaxf(xb, 0.f);
        l0 = fmaf(w2[0 * 32 + oc], r, l0);
        l1 = fmaf(w2[1 * 32 + oc], r, l1);
        l2 = fmaf(w2[2 * 32 + oc], r, l2);
    }
    float t = fmaxf(temp[0], 0.1f);
    float it = 1.0f / t;
    l0 *= it; l1 *= it; l2 *= it;
    float m = fmaxf(l0, fmaxf(l1, l2));
    float e0 = __expf(l0 - m), e1 = __expf(l1 - m), e2 = __expf(l2 - m);
    float is = 1.0f / (e0 + e1 + e2);
    swp[0 * (B_ * HW_) + pid] = e0 * is;
    swp[1 * (B_ * HW_) + pid] = e1 * is;
    swp[2 * (B_ * HW_) + pid] = e2 * is;
}

// ---------------------------------------------------------------------------
// Kernel 4: MFMA 32x32x16 fused conv. (Round-0 register structure, 2x grid)
//  Wave = 32 consecutive w at fixed (b,h), sweeping 12 d values.
//  A[m=lane&31][kk=(lane>>5)*8+j]: lane loads 8 gi-halfs of tap T(c,hf) at
//  row w0+m. softmax weight sw_k(h, w0+m) is folded into A (f16 mul), so a
//  single accumulator chain (split in 2 for MFMA latency) covers all scales.
//  D: col = lane&31 = o, row = (reg&3)+8*(reg>>2)+4*hf = w-offset.
// block 256 = 4 waves = (2 h) x (2 d-quarters); grid = (6, 48, B*2):
//  blockIdx.z = b*2 + dhalf; wave's d0 = dhalf*24 + dh*12, 12-d sweep.
// 1152 blocks (4.5 blocks/CU): raises occupancy WITHOUT changing per-wave
// register structure (Round-1's launch_bounds(256,4) forced scratch spills:
// VGPR 120->64, WRITE_SIZE 221->362 MB — do not repeat).
// ---------------------------------------------------------------------------
__global__ __launch_bounds__(256, 2) void fusedconv_mfma32(
        const _Float16* __restrict__ baseh,
        const float* __restrict__ swp,
        const _Float16* __restrict__ bpack,
        const float* __restrict__ bf,
        float* __restrict__ out) {
    int tid = threadIdx.x;
    int wave = tid >> 6, lane = tid & 63;
    int m = lane & 31, hf = lane >> 5;
    int hh = wave >> 1, dh = wave & 1;
    int w0 = blockIdx.x * 32;
    int h  = blockIdx.y * 2 + hh;
    int b  = blockIdx.z >> 1;
    int dq = blockIdx.z & 1;
    int d0 = dq * 24 + dh * 12;

    // resident B fragments: 3 scales x 14 K-chunks
    f16x8 Bf[3][14];
    #pragma unroll
    for (int k = 0; k < 3; ++k)
        #pragma unroll
        for (int c = 0; c < 14; ++c)
            Bf[k][c] = *(const f16x8*)(bpack + ((k * 14 + c) * 64 + lane) * 8);

    // softmax weights as f16 splats (per-lane row m)
    f16x8 swh[3];
    #pragma unroll
    for (int k = 0; k < 3; ++k) {
        float s = swp[k * (B_ * HW_) + b * HW_ + h * W_ + w0 + m];
        _Float16 hs = (_Float16)s;
        f16x8 t;
        #pragma unroll
        for (int j = 0; j < 8; ++j) t[j] = hs;
        swh[k] = t;
    }

    // half-wave address deltas per (scale, class), bytes
    int hdv[3][4];
    #pragma unroll
    for (int k = 0; k < 3; ++k) {
        int dil = 1 << k;
        hdv[k][0] = hf * (2 * dil * HP_ * WP_ * 8 * 2);
        hdv[k][1] = hf * (2 * dil * WP_ * 8 * 2);
        hdv[k][2] = hf * (2 * dil * 8 * 2);
        hdv[k][3] = 0;
    }

    const char* bb = (const char*)baseh;
    char*       ob = (char*)out;

    // byte offset of interior origin (d0-plane, h, w0+m)
    unsigned pm = (unsigned)(((((b * DP_ + 4 + d0) * HP_ + 4 + h) * WP_ + 4 + w0 + m) * 8) * 2);
    float bias = bf[m];   // o = lane&31
    unsigned outoff = (unsigned)((((b * OUT_ + m) * D_ + d0) * HW_ + h * W_ + w0 + 4 * hf) * 4);

    for (int d = 0; d < 12; ++d) {
        f32x16 acc0 = {0.f}, acc1 = {0.f};
        #pragma unroll
        for (int i = 0; i < 16; ++i) { acc0[i] = 0.f; acc1[i] = 0.f; }
        #pragma unroll
        for (int k = 0; k < 3; ++k) {
            int dil = 1 << k;
            #pragma unroll
            for (int c = 0; c < 14; ++c) {
                int coff, cls;
                if (c < 9)        { coff = ((-dil * HP_ + (c / 3 - 1) * dil) * WP_ * 8 + (c % 3 - 1) * dil * 8) * 2; cls = 0; }
                else if (c < 12)  { coff = ((-dil) * WP_ * 8 + ((c - 9) - 1) * dil * 8) * 2;                          cls = 1; }
                else if (c == 12) { coff = -dil * 16;                                                                  cls = 2; }
                else              { coff = 0;                                                                          cls = 3; }
                unsigned a = pm + (unsigned)(hdv[k][cls] + coff);
                f16x8 av = *(const f16x8*)(bb + a);
                av = av * swh[k];
                if (c & 1) acc1 = __builtin_amdgcn_mfma_f32_32x32x16_f16(av, Bf[k][c], acc1, 0, 0, 0);
                else       acc0 = __builtin_amdgcn_mfma_f32_32x32x16_f16(av, Bf[k][c], acc0, 0, 0, 0);
            }
        }
        #pragma unroll
        for (int q = 0; q < 4; ++q) {
            f32x4 v;
            #pragma unroll
            for (int i = 0; i < 4; ++i) v[i] = acc0[4 * q + i] + acc1[4 * q + i] + bias;
            *(f32x4*)(ob + outoff + q * 32) = v;   // rows 8q+4hf..+3, o = m
        }
        pm += PLANE_ * 2;
        outoff += HW_ * 4;
    }
}

// ---------------------------------------------------------------------------
extern "C" void kernel_launch(void* const* d_in, const int* in_sizes, int n_in,
                              void* d_out, int out_size, void* d_ws, size_t ws_size,
                              hipStream_t stream) {
    const float* feat_l   = (const float*)d_in[0];
    const float* feat_r   = (const float*)d_in[1];
    const float* edge     = (const float*)d_in[2];
    const float* w_pred1  = (const float*)d_in[3];
    const float* bn_gamma = (const float*)d_in[4];
    const float* bn_beta  = (const float*)d_in[5];
    const float* bn_mean  = (const float*)d_in[6];
    const float* bn_var   = (const float*)d_in[7];
    const float* w_pred2  = (const float*)d_in[8];
    const float* b_pred2  = (const float*)d_in[9];
    const float* temp     = (const float*)d_in[10];
    const float* w_s      = (const float*)d_in[11];
    const float* w_m      = (const float*)d_in[12];
    const float* w_l      = (const float*)d_in[13];
    const float* w_final  = (const float*)d_in[14];
    const float* b_final  = (const float*)d_in[15];
    float* out = (float*)d_out;

    float* ws = (float*)d_ws;
    float*     fln   = ws + OFF_FLN;
    float*     frn   = ws + OFF_FRN;
    _Float16*  baseh = (_Float16*)(ws + OFF_BASEH);
    float*     swp   = ws + OFF_SW;
    _Float16*  bpack = (_Float16*)(ws + OFF_BPACK);
    float*     wp1T  = ws + OFF_WP1T;

    // 0: weight prep
    wtrans_kernel<<<dim3(158), 256, 0, stream>>>(w_s, w_m, w_l, w_final, w_pred1, bpack, wp1T);
    // zero the padded volume (halo must be 0; ws is poisoned each launch)
    hipMemsetAsync(baseh, 0, (size_t)BASEH_HALFS * sizeof(_Float16), stream);
    // 1: normalize
    norm_kernel<<<dim3(HW_ / 256, B_ * G_, 2), 256, 0, stream>>>(feat_l, feat_r, fln, frn);
    // 2: correlation volume -> padded f16
    corr_kernel<<<dim3(W_ / 32, H_, B_), 256, 0, stream>>>(fln, frn, baseh);
    // 3: pred path -> softmax planes
    pred_kernel<<<dim3(B_ * HW_ / 256), 256, 0, stream>>>(feat_l, edge, wp1T, bn_gamma,
                                                          bn_beta, bn_mean, bn_var,
                                                          w_pred2, b_pred2, temp, swp);
    // 4: MFMA 32x32 fused conv (2x grid along d; per-wave structure = Round 0)
    fusedconv_mfma32<<<dim3(W_ / 32, H_ / 2, B_ * 2), 256, 0, stream>>>(baseh, swp, bpack, b_final, out);
}

// Round 3
// 543.865 us; speedup vs baseline: 1.4114x; 1.1564x over previous
//
#include <hip/hip_runtime.h>
#include <hip/hip_bf16.h>

// Problem constants
#define B_   2
#define C_   64
#define H_   96
#define W_   192
#define D_   48
#define G_   8
#define OUT_ 32
#define HW_  (H_ * W_)   // 18432

// Padded f16 correlation volume: (B, DP, HP, WP, 8) halfs, halo = 4
#define DP_ 56
#define HP_ 104
#define WP_ 200
#define PLANE_ (HP_ * WP_ * 8)          // halfs per d-plane = 166400
#define BASEH_HALFS (B_ * DP_ * PLANE_) // 18,636,800 halfs = 37.27 MB

// Workspace layout (float offsets)
#define OFF_FLN   0                        // (B,G,H,W,8) fp32       2,359,296
#define OFF_FRN   2359296                  // (B,G,H,W,8) fp32       2,359,296
#define OFF_BASEH 4718592                  // f16 padded volume      9,318,400 float-slots
#define OFF_SW    14036992                 // (3,B*HW) fp32            110,592
#define OFF_BPACK 14147584                 // f16 B-frags               10,752 float-slots
#define OFF_WP1T  14158336                 // (65,9,32) fp32            18,720

typedef _Float16 f16x8  __attribute__((ext_vector_type(8)));
typedef float    f32x4  __attribute__((ext_vector_type(4)));
typedef float    f32x16 __attribute__((ext_vector_type(16)));

// ---------------------------------------------------------------------------
// Kernel 0: weight prep for 32x32x16 MFMA.
//  bpack[((k*14+c)*64+lane)*8+j] = f16( V_k[tap(c,hf)][gi=j][n=lane&31] )
//  hf = lane>>5. Chunk->tap mapping (must match fused kernel's addressing):
//   c in [0,9):  kd = hf? +1 : -1 ; kh = c/3-1 ; kw = c%3-1
//   c in [9,12): kd = 0 ; kh = hf? +1 : -1 ; kw = (c-9)-1
//   c == 12:     kd = 0 ; kh = 0 ; kw = hf? +1 : -1
//   c == 13:     hf==0 -> center (0,0,0) ; hf==1 -> zero pad
//  V_k[tap][gi][n] = sum_g w_final[n*8+g] * w_k[(g*8+gi)*27+tap]
//  part B: wp1T[ic][t][oc] = w_pred1[oc][ic][t]
// ---------------------------------------------------------------------------
__global__ void wtrans_kernel(const float* __restrict__ w_s,
                              const float* __restrict__ w_m,
                              const float* __restrict__ w_l,
                              const float* __restrict__ w_final,
                              const float* __restrict__ w_pred1,
                              _Float16* __restrict__ bpack,
                              float* __restrict__ wp1T) {
    int i = blockIdx.x * 256 + threadIdx.x;
    if (i < 21504) {
        int j = i & 7;                 // gi
        int lane = (i >> 3) & 63;
        int kc = i >> 9;               // 0..41
        int c = kc % 14, k = kc / 14;
        int hf = lane >> 5, n = lane & 31;
        int kd = 0, kh = 0, kw = 0; bool valid = true;
        if (c < 9)        { kd = hf ? 1 : -1; kh = c / 3 - 1; kw = c % 3 - 1; }
        else if (c < 12)  { kd = 0; kh = hf ? 1 : -1; kw = (c - 9) - 1; }
        else if (c == 12) { kd = 0; kh = 0; kw = hf ? 1 : -1; }
        else              { valid = (hf == 0); }
        float val = 0.f;
        if (valid) {
            int tap = (kd + 1) * 9 + (kh + 1) * 3 + (kw + 1);
            const float* wsel = (k == 0) ? w_s : (k == 1) ? w_m : w_l;
            #pragma unroll
            for (int g = 0; g < 8; ++g)
                val += w_final[n * 8 + g] * wsel[(g * 8 + j) * 27 + tap];
        }
        bpack[i] = (_Float16)val;
    } else if (i < 21504 + 18720) {
        int j = i - 21504;
        int oc = j & 31; int it = j >> 5; int ic = it / 9; int t = it - ic * 9;
        wp1T[j] = w_pred1[(oc * 65 + ic) * 9 + t];
    }
}

// ---------------------------------------------------------------------------
// Kernel 1: group-L2-normalize + transpose to channel-last (B,G,H,W,8)
// ---------------------------------------------------------------------------
__global__ __launch_bounds__(256) void norm_kernel(const float* __restrict__ feat_l,
                                                   const float* __restrict__ feat_r,
                                                   float* __restrict__ fln,
                                                   float* __restrict__ frn) {
    int hw = blockIdx.x * 256 + threadIdx.x;
    int bg = blockIdx.y;
    const float* src = blockIdx.z ? feat_r : feat_l;
    float*       dst = blockIdx.z ? frn    : fln;
    float v[8]; float s = 0.f;
    #pragma unroll
    for (int c = 0; c < 8; ++c) {
        v[c] = src[(bg * 8 + c) * HW_ + hw];
        s += v[c] * v[c];
    }
    float inv = 1.0f / fmaxf(sqrtf(s), 1e-12f);
    #pragma unroll
    for (int c = 0; c < 8; ++c) dst[((long)bg * HW_ + hw) * 8 + c] = v[c] * inv;
}

// ---------------------------------------------------------------------------
// Kernel 2: correlation volume -> padded f16 channel-last volume
// ---------------------------------------------------------------------------
__global__ __launch_bounds__(256) void corr_kernel(const float* __restrict__ fln,
                                                   const float* __restrict__ frn,
                                                   _Float16* __restrict__ baseh) {
    int tid = threadIdx.x;
    int g = tid & 7, wi = tid >> 3;
    int w = blockIdx.x * 32 + wi;
    int h = blockIdx.y;
    int b = blockIdx.z;
    const float* flp  = fln + (size_t)((((b * G_ + g) * H_ + h) * W_ + w)) * 8;
    const float* frow = frn + (size_t)((((b * G_ + g) * H_ + h) * W_)) * 8;
    f32x4 a0 = *(const f32x4*)(flp);
    f32x4 a1 = *(const f32x4*)(flp + 4);
    const float inv = 0.35355339059327373f;  // 1/sqrt(8)
    _Float16* dst = baseh + (size_t)((b * DP_ + 4) * HP_ + 4 + h) * WP_ * 8 + (size_t)(4 + w) * 8 + g;
    for (int d = 0; d < D_; ++d) {
        int wd = w - d;
        float acc = 0.f;
        if (wd >= 0) {
            f32x4 b0 = *(const f32x4*)(frow + wd * 8);
            f32x4 b1 = *(const f32x4*)(frow + wd * 8 + 4);
            acc = a0[0]*b0[0] + a0[1]*b0[1] + a0[2]*b0[2] + a0[3]*b0[3]
                + a1[0]*b1[0] + a1[1]*b1[1] + a1[2]*b1[2] + a1[3]*b1[3];
            acc *= inv;
        }
        dst[(size_t)d * PLANE_] = (_Float16)acc;
    }
}

// ---------------------------------------------------------------------------
// Kernel 3: 2D conv(65->32,3x3)+BN+relu+1x1(32->3)+softmax -> 3 planes swp[k]
// ---------------------------------------------------------------------------
__global__ __launch_bounds__(256) void pred_kernel(const float* __restrict__ feat_l,
                                                   const float* __restrict__ edge,
                                                   const float* __restrict__ wp1T,
                                                   const float* __restrict__ gamma,
                                                   const float* __restrict__ beta,
                                                   const float* __restrict__ mean,
                                                   const float* __restrict__ var,
                                                   const float* __restrict__ w2,
                                                   const float* __restrict__ b2,
                                                   const float* __restrict__ temp,
                                                   float* __restrict__ swp) {
    int pid = blockIdx.x * 256 + threadIdx.x;   // 0..36863
    int b = pid / HW_; int hw = pid - b * HW_;
    int h = hw / W_;   int w = hw - h * W_;

    float acc[32];
    #pragma unroll
    for (int i = 0; i < 32; ++i) acc[i] = 0.f;

    for (int ic = 0; ic < 65; ++ic) {
        const float* src = (ic < 64) ? (feat_l + (size_t)(b * 64 + ic) * HW_)
                                     : (edge + (size_t)b * HW_);
        float v[9];
        #pragma unroll
        for (int ky = 0; ky < 3; ++ky) {
            int y = h + ky - 1;
            #pragma unroll
            for (int kx = 0; kx < 3; ++kx) {
                int x = w + kx - 1;
                bool ok = (y >= 0) && (y < H_) && (x >= 0) && (x < W_);
                v[ky * 3 + kx] = ok ? src[y * W_ + x] : 0.f;
            }
        }
        #pragma unroll
        for (int t = 0; t < 9; ++t) {
            const float* wrow = wp1T + (ic * 9 + t) * 32;
            float vv = v[t];
            #pragma unroll
            for (int oc = 0; oc < 32; ++oc) acc[oc] = fmaf(vv, wrow[oc], acc[oc]);
        }
    }

    float l0 = b2[0], l1 = b2[1], l2 = b2[2];
    #pragma unroll
    for (int oc = 0; oc < 32; ++oc) {
        float sc = gamma[oc] / sqrtf(var[oc] + 1e-5f);
        float xb = (acc[oc] - mean[oc]) * sc + beta[oc];
        float r = fmaxf(xb, 0.f);
        l0 = fmaf(w2[0 * 32 + oc], r, l0);
        l1 = fmaf(w2[1 * 32 + oc], r, l1);
        l2 = fmaf(w2[2 * 32 + oc], r, l2);
    }
    float t = fmaxf(temp[0], 0.1f);
    float it = 1.0f / t;
    l0 *= it; l1 *= it; l2 *= it;
    float m = fmaxf(l0, fmaxf(l1, l2));
    float e0 = __expf(l0 - m), e1 = __expf(l1 - m), e2 = __expf(l2 - m);
    float is = 1.0f / (e0 + e1 + e2);
    swp[0 * (B_ * HW_) + pid] = e0 * is;
    swp[1 * (B_ * HW_) + pid] = e1 * is;
    swp[2 * (B_ * HW_) + pid] = e2 * is;
}

// ---------------------------------------------------------------------------
// Kernel 4: MFMA 32x32x16 fused conv.  (R2 mapping + LDS-B + XCD swizzle)
//  Wave = 32 consecutive w at fixed (b,h), sweeping 12 d values.
//  A[m=lane&31][kk=(lane>>5)*8+j]: lane loads 8 gi-halfs of tap T(c,hf) at
//  row w0+m; softmax weight folded into A (f16 mul). 2 interleaved acc chains.
//  B fragments: staged ONCE per block into LDS (43 KB) and read per-MFMA with
//  ds_read_b128 (linear layout -> conflict-free). This frees the ~168 regs the
//  R0/R2 versions burned on resident Bf (true footprint ~300 regs -> 1.5
//  waves/SIMD). An opaque-index asm inside the d-loop defeats LICM so the
//  compiler cannot hoist the 42 LDS reads back into registers.
//  XCD swizzle: nwg=1152 (%8==0), xcd gets 144 consecutive work-items =
//  24 adjacent h at one (b,dq) -> ~3.3 MB working set, fits 4 MB XCD-L2.
//  D: col = lane&31 = o, row = (reg&3)+8*(reg>>2)+4*hf = w-offset.
// block 256 = 4 waves = (2 h) x (2 d-chunks); grid = (6, 48, B*2)
// ---------------------------------------------------------------------------
__global__ __launch_bounds__(256, 2) void fusedconv_mfma32(
        const _Float16* __restrict__ baseh,
        const float* __restrict__ swp,
        const _Float16* __restrict__ bpack,
        const float* __restrict__ bf,
        float* __restrict__ out) {
    __shared__ _Float16 bsh[3 * 14 * 64 * 8];   // 43,008 B

    int tid = threadIdx.x;
    // stage bpack -> LDS (2688 f16x8 chunks)
    {
        const f16x8* srcv = (const f16x8*)bpack;
        f16x8* dstv = (f16x8*)bsh;
        for (int i = tid; i < 2688; i += 256) dstv[i] = srcv[i];
    }

    // XCD-aware bijective swizzle of the linear block id
    int L   = blockIdx.x + 6 * (blockIdx.y + 48 * blockIdx.z);
    int sL  = (L & 7) * 144 + (L >> 3);
    int bx  = sL % 6;
    int byz = sL / 6;
    int by  = byz % 48;
    int bz  = byz / 48;

    int wave = tid >> 6, lane = tid & 63;
    int m = lane & 31, hf = lane >> 5;
    int hh = wave >> 1, dh = wave & 1;
    int w0 = bx * 32;
    int h  = by * 2 + hh;
    int b  = bz >> 1;
    int dq = bz & 1;
    int d0 = dq * 24 + dh * 12;

    // softmax weights as f16 splats (per-lane row m)
    f16x8 swh[3];
    #pragma unroll
    for (int k = 0; k < 3; ++k) {
        float s = swp[k * (B_ * HW_) + b * HW_ + h * W_ + w0 + m];
        _Float16 hs = (_Float16)s;
        f16x8 t;
        #pragma unroll
        for (int j = 0; j < 8; ++j) t[j] = hs;
        swh[k] = t;
    }

    // half-wave address deltas per (scale, class), bytes
    int hdv[3][4];
    #pragma unroll
    for (int k = 0; k < 3; ++k) {
        int dil = 1 << k;
        hdv[k][0] = hf * (2 * dil * HP_ * WP_ * 8 * 2);
        hdv[k][1] = hf * (2 * dil * WP_ * 8 * 2);
        hdv[k][2] = hf * (2 * dil * 8 * 2);
        hdv[k][3] = 0;
    }

    const char* bb = (const char*)baseh;
    char*       ob = (char*)out;

    // byte offset of interior origin (d0-plane, h, w0+m)
    unsigned pm = (unsigned)(((((b * DP_ + 4 + d0) * HP_ + 4 + h) * WP_ + 4 + w0 + m) * 8) * 2);
    float bias = bf[m];   // o = lane&31
    unsigned outoff = (unsigned)((((b * OUT_ + m) * D_ + d0) * HW_ + h * W_ + w0 + 4 * hf) * 4);

    __syncthreads();

    for (int d = 0; d < 12; ++d) {
        // opaque per-iteration LDS byte offset (value 0): defeats LICM/hoist
        unsigned bofs = (unsigned)(lane * 16);
        asm volatile("" : "+v"(bofs));
        const char* bshp = (const char*)bsh + bofs;

        f32x16 acc0, acc1;
        #pragma unroll
        for (int i = 0; i < 16; ++i) { acc0[i] = 0.f; acc1[i] = 0.f; }
        #pragma unroll
        for (int k = 0; k < 3; ++k) {
            int dil = 1 << k;
            #pragma unroll
            for (int c = 0; c < 14; ++c) {
                int coff, cls;
                if (c < 9)        { coff = ((-dil * HP_ + (c / 3 - 1) * dil) * WP_ * 8 + (c % 3 - 1) * dil * 8) * 2; cls = 0; }
                else if (c < 12)  { coff = ((-dil) * WP_ * 8 + ((c - 9) - 1) * dil * 8) * 2;                          cls = 1; }
                else if (c == 12) { coff = -dil * 16;                                                                  cls = 2; }
                else              { coff = 0;                                                                          cls = 3; }
                unsigned a = pm + (unsigned)(hdv[k][cls] + coff);
                f16x8 av = *(const f16x8*)(bb + a);
                f16x8 Bv = *(const f16x8*)(bshp + (k * 14 + c) * 1024);
                av = av * swh[k];
                if (c & 1) acc1 = __builtin_amdgcn_mfma_f32_32x32x16_f16(av, Bv, acc1, 0, 0, 0);
                else       acc0 = __builtin_amdgcn_mfma_f32_32x32x16_f16(av, Bv, acc0, 0, 0, 0);
            }
        }
        #pragma unroll
        for (int q = 0; q < 4; ++q) {
            f32x4 v;
            #pragma unroll
            for (int i = 0; i < 4; ++i) v[i] = acc0[4 * q + i] + acc1[4 * q + i] + bias;
            *(f32x4*)(ob + outoff + q * 32) = v;   // rows 8q+4hf..+3, o = m
        }
        pm += PLANE_ * 2;
        outoff += HW_ * 4;
    }
}

// ---------------------------------------------------------------------------
extern "C" void kernel_launch(void* const* d_in, const int* in_sizes, int n_in,
                              void* d_out, int out_size, void* d_ws, size_t ws_size,
                              hipStream_t stream) {
    const float* feat_l   = (const float*)d_in[0];
    const float* feat_r   = (const float*)d_in[1];
    const float* edge     = (const float*)d_in[2];
    const float* w_pred1  = (const float*)d_in[3];
    const float* bn_gamma = (const float*)d_in[4];
    const float* bn_beta  = (const float*)d_in[5];
    const float* bn_mean  = (const float*)d_in[6];
    const float* bn_var   = (const float*)d_in[7];
    const float* w_pred2  = (const float*)d_in[8];
    const float* b_pred2  = (const float*)d_in[9];
    const float* temp     = (const float*)d_in[10];
    const float* w_s      = (const float*)d_in[11];
    const float* w_m      = (const float*)d_in[12];
    const float* w_l      = (const float*)d_in[13];
    const float* w_final  = (const float*)d_in[14];
    const float* b_final  = (const float*)d_in[15];
    float* out = (float*)d_out;

    float* ws = (float*)d_ws;
    float*     fln   = ws + OFF_FLN;
    float*     frn   = ws + OFF_FRN;
    _Float16*  baseh = (_Float16*)(ws + OFF_BASEH);
    float*     swp   = ws + OFF_SW;
    _Float16*  bpack = (_Float16*)(ws + OFF_BPACK);
    float*     wp1T  = ws + OFF_WP1T;

    // 0: weight prep
    wtrans_kernel<<<dim3(158), 256, 0, stream>>>(w_s, w_m, w_l, w_final, w_pred1, bpack, wp1T);
    // zero the padded volume (halo must be 0; ws is poisoned each launch)
    hipMemsetAsync(baseh, 0, (size_t)BASEH_HALFS * sizeof(_Float16), stream);
    // 1: normalize
    norm_kernel<<<dim3(HW_ / 256, B_ * G_, 2), 256, 0, stream>>>(feat_l, feat_r, fln, frn);
    // 2: correlation volume -> padded f16
    corr_kernel<<<dim3(W_ / 32, H_, B_), 256, 0, stream>>>(fln, frn, baseh);
    // 3: pred path -> softmax planes
    pred_kernel<<<dim3(B_ * HW_ / 256), 256, 0, stream>>>(feat_l, edge, wp1T, bn_gamma,
                                                          bn_beta, bn_mean, bn_var,
                                                          w_pred2, b_pred2, temp, swp);
    // 4: MFMA 32x32 fused conv (LDS-B + XCD swizzle)
    fusedconv_mfma32<<<dim3(W_ / 32, H_ / 2, B_ * 2), 256, 0, stream>>>(baseh, swp, bpack, b_final, out);
}

// Round 4
// 533.089 us; speedup vs baseline: 1.4399x; 1.0202x over previous
//
#include <hip/hip_runtime.h>
#include <hip/hip_bf16.h>

// Problem constants
#define B_   2
#define C_   64
#define H_   96
#define W_   192
#define D_   48
#define G_   8
#define OUT_ 32
#define HW_  (H_ * W_)   // 18432

// Padded f16 correlation volume: (B, DP, HP, WP, 8) halfs, halo = 4
#define DP_ 56
#define HP_ 104
#define WP_ 200
#define PLANE_ (HP_ * WP_ * 8)          // halfs per d-plane = 166400
#define BASEH_HALFS (B_ * DP_ * PLANE_) // 18,636,800 halfs = 37.27 MB

// Workspace layout (float offsets)
#define OFF_FLN   0                        // (unused since R4: norm fused into corr)
#define OFF_FRN   2359296                  // (unused since R4)
#define OFF_BASEH 4718592                  // f16 padded volume      9,318,400 float-slots
#define OFF_SW    14036992                 // (3,B*HW) fp32            110,592
#define OFF_BPACK 14147584                 // f16 B-frags               10,752 float-slots
#define OFF_WP1T  14158336                 // (65,9,32) fp32            18,720

typedef _Float16 f16x8  __attribute__((ext_vector_type(8)));
typedef float    f32x4  __attribute__((ext_vector_type(4)));
typedef float    f32x16 __attribute__((ext_vector_type(16)));

// ---------------------------------------------------------------------------
// Kernel 0: weight prep for 32x32x16 MFMA.
//  bpack[((k*14+c)*64+lane)*8+j] = f16( V_k[tap(c,hf)][gi=j][n=lane&31] )
//  hf = lane>>5. Chunk->tap mapping (must match fused kernel's addressing):
//   c in [0,9):  kd = hf? +1 : -1 ; kh = c/3-1 ; kw = c%3-1
//   c in [9,12): kd = 0 ; kh = hf? +1 : -1 ; kw = (c-9)-1
//   c == 12:     kd = 0 ; kh = 0 ; kw = hf? +1 : -1
//   c == 13:     hf==0 -> center (0,0,0) ; hf==1 -> zero pad
//  V_k[tap][gi][n] = sum_g w_final[n*8+g] * w_k[(g*8+gi)*27+tap]
//  part B: wp1T[ic][t][oc] = w_pred1[oc][ic][t]
// ---------------------------------------------------------------------------
__global__ void wtrans_kernel(const float* __restrict__ w_s,
                              const float* __restrict__ w_m,
                              const float* __restrict__ w_l,
                              const float* __restrict__ w_final,
                              const float* __restrict__ w_pred1,
                              _Float16* __restrict__ bpack,
                              float* __restrict__ wp1T) {
    int i = blockIdx.x * 256 + threadIdx.x;
    if (i < 21504) {
        int j = i & 7;                 // gi
        int lane = (i >> 3) & 63;
        int kc = i >> 9;               // 0..41
        int c = kc % 14, k = kc / 14;
        int hf = lane >> 5, n = lane & 31;
        int kd = 0, kh = 0, kw = 0; bool valid = true;
        if (c < 9)        { kd = hf ? 1 : -1; kh = c / 3 - 1; kw = c % 3 - 1; }
        else if (c < 12)  { kd = 0; kh = hf ? 1 : -1; kw = (c - 9) - 1; }
        else if (c == 12) { kd = 0; kh = 0; kw = hf ? 1 : -1; }
        else              { valid = (hf == 0); }
        float val = 0.f;
        if (valid) {
            int tap = (kd + 1) * 9 + (kh + 1) * 3 + (kw + 1);
            const float* wsel = (k == 0) ? w_s : (k == 1) ? w_m : w_l;
            #pragma unroll
            for (int g = 0; g < 8; ++g)
                val += w_final[n * 8 + g] * wsel[(g * 8 + j) * 27 + tap];
        }
        bpack[i] = (_Float16)val;
    } else if (i < 21504 + 18720) {
        int j = i - 21504;
        int oc = j & 31; int it = j >> 5; int ic = it / 9; int t = it - ic * 9;
        wp1T[j] = w_pred1[(oc * 65 + ic) * 9 + t];
    }
}

// ---------------------------------------------------------------------------
// Kernel 2 (R4: norm fused in): correlation volume -> padded f16 volume.
//  Block = (32 w at bx) x (8 g) at one (h,b). Stages the 80-column feat_r
//  window [w0-48, w0+32) into LDS, L2-normalizing each (g,w) 8-vector on the
//  fly (1/sqrt(8) corr scale folded into the stored values). Own fl vector is
//  normalized in registers. Eliminates the separate norm kernel and the
//  75 MB fln/frn round-trip.
//  LDS layout frl[iw*68 + g*8 + c]: stride 68 staggers banks (~4-way max).
// ---------------------------------------------------------------------------
__global__ __launch_bounds__(256) void corr_kernel(const float* __restrict__ feat_l,
                                                   const float* __restrict__ feat_r,
                                                   _Float16* __restrict__ baseh) {
    __shared__ float frl[80 * 68];   // 21,760 B
    int tid = threadIdx.x;
    int h = blockIdx.y;
    int b = blockIdx.z;
    int w0 = blockIdx.x * 32;
    int wbase = w0 - 48;             // LDS window start (may be < 0)

    // stage + normalize feat_r window: 8 g x 80 iw pairs
    for (int p = tid; p < 640; p += 256) {
        int gg = p / 80;
        int iw = p - gg * 80;
        int wg = wbase + iw;
        if (wg >= 0) {
            const float* src = feat_r + (size_t)(b * 64 + gg * 8) * HW_ + h * W_ + wg;
            float v[8]; float s = 0.f;
            #pragma unroll
            for (int c = 0; c < 8; ++c) { v[c] = src[(size_t)c * HW_]; s += v[c] * v[c]; }
            float inv = 0.35355339059327373f / fmaxf(sqrtf(s), 1e-12f);  // incl 1/sqrt(8)
            #pragma unroll
            for (int c = 0; c < 8; ++c) frl[iw * 68 + gg * 8 + c] = v[c] * inv;
        }
    }

    // own fl vector, normalized (no 1/sqrt(8) here)
    int g = tid & 7, wi = tid >> 3;
    int w = w0 + wi;
    const float* fls = feat_l + (size_t)(b * 64 + g * 8) * HW_ + h * W_ + w;
    float a[8]; float s = 0.f;
    #pragma unroll
    for (int c = 0; c < 8; ++c) { a[c] = fls[(size_t)c * HW_]; s += a[c] * a[c]; }
    float inv = 1.0f / fmaxf(sqrtf(s), 1e-12f);
    #pragma unroll
    for (int c = 0; c < 8; ++c) a[c] *= inv;

    __syncthreads();

    _Float16* dst = baseh + (size_t)((b * DP_ + 4) * HP_ + 4 + h) * WP_ * 8 + (size_t)(4 + w) * 8 + g;
    for (int d = 0; d < D_; ++d) {
        int wd = w - d;
        float acc = 0.f;
        if (wd >= 0) {
            const float* fr = frl + (wd - wbase) * 68 + g * 8;
            acc = a[0]*fr[0] + a[1]*fr[1] + a[2]*fr[2] + a[3]*fr[3]
                + a[4]*fr[4] + a[5]*fr[5] + a[6]*fr[6] + a[7]*fr[7];
        }
        dst[(size_t)d * PLANE_] = (_Float16)acc;
    }
}

// ---------------------------------------------------------------------------
// Kernel 3: 2D conv(65->32,3x3)+BN+relu+1x1(32->3)+softmax -> 3 planes swp[k]
// ---------------------------------------------------------------------------
__global__ __launch_bounds__(256) void pred_kernel(const float* __restrict__ feat_l,
                                                   const float* __restrict__ edge,
                                                   const float* __restrict__ wp1T,
                                                   const float* __restrict__ gamma,
                                                   const float* __restrict__ beta,
                                                   const float* __restrict__ mean,
                                                   const float* __restrict__ var,
                                                   const float* __restrict__ w2,
                                                   const float* __restrict__ b2,
                                                   const float* __restrict__ temp,
                                                   float* __restrict__ swp) {
    int pid = blockIdx.x * 256 + threadIdx.x;   // 0..36863
    int b = pid / HW_; int hw = pid - b * HW_;
    int h = hw / W_;   int w = hw - h * W_;

    float acc[32];
    #pragma unroll
    for (int i = 0; i < 32; ++i) acc[i] = 0.f;

    for (int ic = 0; ic < 65; ++ic) {
        const float* src = (ic < 64) ? (feat_l + (size_t)(b * 64 + ic) * HW_)
                                     : (edge + (size_t)b * HW_);
        float v[9];
        #pragma unroll
        for (int ky = 0; ky < 3; ++ky) {
            int y = h + ky - 1;
            #pragma unroll
            for (int kx = 0; kx < 3; ++kx) {
                int x = w + kx - 1;
                bool ok = (y >= 0) && (y < H_) && (x >= 0) && (x < W_);
                v[ky * 3 + kx] = ok ? src[y * W_ + x] : 0.f;
            }
        }
        #pragma unroll
        for (int t = 0; t < 9; ++t) {
            const float* wrow = wp1T + (ic * 9 + t) * 32;
            float vv = v[t];
            #pragma unroll
            for (int oc = 0; oc < 32; ++oc) acc[oc] = fmaf(vv, wrow[oc], acc[oc]);
        }
    }

    float l0 = b2[0], l1 = b2[1], l2 = b2[2];
    #pragma unroll
    for (int oc = 0; oc < 32; ++oc) {
        float sc = gamma[oc] / sqrtf(var[oc] + 1e-5f);
        float xb = (acc[oc] - mean[oc]) * sc + beta[oc];
        float r = fmaxf(xb, 0.f);
        l0 = fmaf(w2[0 * 32 + oc], r, l0);
        l1 = fmaf(w2[1 * 32 + oc], r, l1);
        l2 = fmaf(w2[2 * 32 + oc], r, l2);
    }
    float t = fmaxf(temp[0], 0.1f);
    float it = 1.0f / t;
    l0 *= it; l1 *= it; l2 *= it;
    float m = fmaxf(l0, fmaxf(l1, l2));
    float e0 = __expf(l0 - m), e1 = __expf(l1 - m), e2 = __expf(l2 - m);
    float is = 1.0f / (e0 + e1 + e2);
    swp[0 * (B_ * HW_) + pid] = e0 * is;
    swp[1 * (B_ * HW_) + pid] = e1 * is;
    swp[2 * (B_ * HW_) + pid] = e2 * is;
}

// ---------------------------------------------------------------------------
// Kernel 4: MFMA 32x32x16 fused conv.  (R3 structure, 512-thread blocks)
//  Wave = 32 consecutive w at fixed (b,h), sweeping 12 d values.
//  A[m=lane&31][kk=(lane>>5)*8+j]: lane loads 8 gi-halfs of tap T(c,hf) at
//  row w0+m; softmax weight folded into A (f16 mul). 2 interleaved acc chains.
//  B fragments in LDS (43 KB/block, staged once, ds_read_b128 linear).
//  512 threads = 8 waves = (4 h) x (2 d-chunks): one B-copy serves 8 waves,
//  so LDS/CU = 2x43 KB at 16 waves/CU (VGPR ~120 -> 4 waves/SIMD) vs R3's
//  3 blocks x 4 waves = 12 waves/CU. +33% residency; 4 adjacent h rows also
//  share taps in L1. Per-wave register structure unchanged (R1 lesson: do
//  NOT force VGPR caps; R2 lesson: occupancy via grid/block shape only).
//  XCD swizzle: nwg=576 (%8==0), chunk 72 -> 48 adjacent h at one (b,dq),
//  ~5.7 MB working set per XCD-L2.
//  D: col = lane&31 = o, row = (reg&3)+8*(reg>>2)+4*hf = w-offset.
// grid = (6, 24, B*2)
// ---------------------------------------------------------------------------
__global__ __launch_bounds__(512, 2) void fusedconv_mfma32(
        const _Float16* __restrict__ baseh,
        const float* __restrict__ swp,
        const _Float16* __restrict__ bpack,
        const float* __restrict__ bf,
        float* __restrict__ out) {
    __shared__ _Float16 bsh[3 * 14 * 64 * 8];   // 43,008 B

    int tid = threadIdx.x;
    // stage bpack -> LDS (2688 f16x8 chunks)
    {
        const f16x8* srcv = (const f16x8*)bpack;
        f16x8* dstv = (f16x8*)bsh;
        for (int i = tid; i < 2688; i += 512) dstv[i] = srcv[i];
    }

    // XCD-aware bijective swizzle of the linear block id (nwg = 576 = 8*72)
    int L   = blockIdx.x + 6 * (blockIdx.y + 24 * blockIdx.z);
    int sL  = (L & 7) * 72 + (L >> 3);
    int bx  = sL % 6;
    int t2  = sL / 6;
    int by  = t2 % 24;
    int bz  = t2 / 24;

    int wave = tid >> 6, lane = tid & 63;
    int m = lane & 31, hf = lane >> 5;
    int hh = wave >> 1, dh = wave & 1;
    int w0 = bx * 32;
    int h  = by * 4 + hh;
    int b  = bz >> 1;
    int dq = bz & 1;
    int d0 = dq * 24 + dh * 12;

    // softmax weights as f16 splats (per-lane row m)
    f16x8 swh[3];
    #pragma unroll
    for (int k = 0; k < 3; ++k) {
        float s = swp[k * (B_ * HW_) + b * HW_ + h * W_ + w0 + m];
        _Float16 hs = (_Float16)s;
        f16x8 t;
        #pragma unroll
        for (int j = 0; j < 8; ++j) t[j] = hs;
        swh[k] = t;
    }

    // half-wave address deltas per (scale, class), bytes
    int hdv[3][4];
    #pragma unroll
    for (int k = 0; k < 3; ++k) {
        int dil = 1 << k;
        hdv[k][0] = hf * (2 * dil * HP_ * WP_ * 8 * 2);
        hdv[k][1] = hf * (2 * dil * WP_ * 8 * 2);
        hdv[k][2] = hf * (2 * dil * 8 * 2);
        hdv[k][3] = 0;
    }

    const char* bb = (const char*)baseh;
    char*       ob = (char*)out;

    // byte offset of interior origin (d0-plane, h, w0+m)
    unsigned pm = (unsigned)(((((b * DP_ + 4 + d0) * HP_ + 4 + h) * WP_ + 4 + w0 + m) * 8) * 2);
    float bias = bf[m];   // o = lane&31
    unsigned outoff = (unsigned)((((b * OUT_ + m) * D_ + d0) * HW_ + h * W_ + w0 + 4 * hf) * 4);

    __syncthreads();

    for (int d = 0; d < 12; ++d) {
        // opaque per-iteration LDS byte offset (value lane*16): defeats LICM/hoist
        unsigned bofs = (unsigned)(lane * 16);
        asm volatile("" : "+v"(bofs));
        const char* bshp = (const char*)bsh + bofs;

        f32x16 acc0, acc1;
        #pragma unroll
        for (int i = 0; i < 16; ++i) { acc0[i] = 0.f; acc1[i] = 0.f; }
        #pragma unroll
        for (int k = 0; k < 3; ++k) {
            int dil = 1 << k;
            #pragma unroll
            for (int c = 0; c < 14; ++c) {
                int coff, cls;
                if (c < 9)        { coff = ((-dil * HP_ + (c / 3 - 1) * dil) * WP_ * 8 + (c % 3 - 1) * dil * 8) * 2; cls = 0; }
                else if (c < 12)  { coff = ((-dil) * WP_ * 8 + ((c - 9) - 1) * dil * 8) * 2;                          cls = 1; }
                else if (c == 12) { coff = -dil * 16;                                                                  cls = 2; }
                else              { coff = 0;                                                                          cls = 3; }
                unsigned a = pm + (unsigned)(hdv[k][cls] + coff);
                f16x8 av = *(const f16x8*)(bb + a);
                f16x8 Bv = *(const f16x8*)(bshp + (k * 14 + c) * 1024);
                av = av * swh[k];
                if (c & 1) acc1 = __builtin_amdgcn_mfma_f32_32x32x16_f16(av, Bv, acc1, 0, 0, 0);
                else       acc0 = __builtin_amdgcn_mfma_f32_32x32x16_f16(av, Bv, acc0, 0, 0, 0);
            }
        }
        #pragma unroll
        for (int q = 0; q < 4; ++q) {
            f32x4 v;
            #pragma unroll
            for (int i = 0; i < 4; ++i) v[i] = acc0[4 * q + i] + acc1[4 * q + i] + bias;
            *(f32x4*)(ob + outoff + q * 32) = v;   // rows 8q+4hf..+3, o = m
        }
        pm += PLANE_ * 2;
        outoff += HW_ * 4;
    }
}

// ---------------------------------------------------------------------------
extern "C" void kernel_launch(void* const* d_in, const int* in_sizes, int n_in,
                              void* d_out, int out_size, void* d_ws, size_t ws_size,
                              hipStream_t stream) {
    const float* feat_l   = (const float*)d_in[0];
    const float* feat_r   = (const float*)d_in[1];
    const float* edge     = (const float*)d_in[2];
    const float* w_pred1  = (const float*)d_in[3];
    const float* bn_gamma = (const float*)d_in[4];
    const float* bn_beta  = (const float*)d_in[5];
    const float* bn_mean  = (const float*)d_in[6];
    const float* bn_var   = (const float*)d_in[7];
    const float* w_pred2  = (const float*)d_in[8];
    const float* b_pred2  = (const float*)d_in[9];
    const float* temp     = (const float*)d_in[10];
    const float* w_s      = (const float*)d_in[11];
    const float* w_m      = (const float*)d_in[12];
    const float* w_l      = (const float*)d_in[13];
    const float* w_final  = (const float*)d_in[14];
    const float* b_final  = (const float*)d_in[15];
    float* out = (float*)d_out;

    float* ws = (float*)d_ws;
    _Float16*  baseh = (_Float16*)(ws + OFF_BASEH);
    float*     swp   = ws + OFF_SW;
    _Float16*  bpack = (_Float16*)(ws + OFF_BPACK);
    float*     wp1T  = ws + OFF_WP1T;

    // 0: weight prep
    wtrans_kernel<<<dim3(158), 256, 0, stream>>>(w_s, w_m, w_l, w_final, w_pred1, bpack, wp1T);
    // zero the padded volume (halo must be 0; ws is poisoned each launch)
    hipMemsetAsync(baseh, 0, (size_t)BASEH_HALFS * sizeof(_Float16), stream);
    // 2: correlation volume -> padded f16 (norm fused in, R4)
    corr_kernel<<<dim3(W_ / 32, H_, B_), 256, 0, stream>>>(feat_l, feat_r, baseh);
    // 3: pred path -> softmax planes
    pred_kernel<<<dim3(B_ * HW_ / 256), 256, 0, stream>>>(feat_l, edge, wp1T, bn_gamma,
                                                          bn_beta, bn_mean, bn_var,
                                                          w_pred2, b_pred2, temp, swp);
    // 4: MFMA 32x32 fused conv (512-thread blocks, LDS-B, XCD swizzle)
    fusedconv_mfma32<<<dim3(W_ / 32, H_ / 4, B_ * 2), 512, 0, stream>>>(baseh, swp, bpack, b_final, out);
}

// Round 5
// 486.507 us; speedup vs baseline: 1.5778x; 1.0957x over previous
//
#include <hip/hip_runtime.h>
#include <hip/hip_bf16.h>

// Problem constants
#define B_   2
#define C_   64
#define H_   96
#define W_   192
#define D_   48
#define G_   8
#define OUT_ 32
#define HW_  (H_ * W_)   // 18432

// Padded f16 correlation volume: (B, DP, HP, WP, 8) halfs, halo = 4
#define DP_ 56
#define HP_ 104
#define WP_ 200
#define PLANE_ (HP_ * WP_ * 8)          // halfs per d-plane = 166400
#define BASEH_HALFS (B_ * DP_ * PLANE_) // 18,636,800 halfs = 37.27 MB

// Workspace layout (float offsets)
#define OFF_BASEH 4718592                  // f16 padded volume      9,318,400 float-slots
#define OFF_SW    14036992                 // (3,B*HW) fp32            110,592
#define OFF_BPACK 14147584                 // f16 B-frags               10,752 float-slots
#define OFF_WP1T  14158336                 // (65,9,32) fp32            18,720

typedef _Float16 f16x8  __attribute__((ext_vector_type(8)));
typedef float    f32x4  __attribute__((ext_vector_type(4)));
typedef float    f32x16 __attribute__((ext_vector_type(16)));

// ---------------------------------------------------------------------------
// Kernel 0: weight prep for 32x32x16 MFMA.
//  bpack[((k*14+c)*64+lane)*8+j] = f16( V_k[tap(c,hf)][gi=j][n=lane&31] )
//  hf = lane>>5. Chunk->tap mapping (must match fused kernel's addressing):
//   c in [0,9):  kd = hf? +1 : -1 ; kh = c/3-1 ; kw = c%3-1
//   c in [9,12): kd = 0 ; kh = hf? +1 : -1 ; kw = (c-9)-1
//   c == 12:     kd = 0 ; kh = 0 ; kw = hf? +1 : -1
//   c == 13:     hf==0 -> center (0,0,0) ; hf==1 -> zero pad
//  V_k[tap][gi][n] = sum_g w_final[n*8+g] * w_k[(g*8+gi)*27+tap]
//  part B: wp1T[ic][t][oc] = w_pred1[oc][ic][t]
// ---------------------------------------------------------------------------
__global__ void wtrans_kernel(const float* __restrict__ w_s,
                              const float* __restrict__ w_m,
                              const float* __restrict__ w_l,
                              const float* __restrict__ w_final,
                              const float* __restrict__ w_pred1,
                              _Float16* __restrict__ bpack,
                              float* __restrict__ wp1T) {
    int i = blockIdx.x * 256 + threadIdx.x;
    if (i < 21504) {
        int j = i & 7;                 // gi
        int lane = (i >> 3) & 63;
        int kc = i >> 9;               // 0..41
        int c = kc % 14, k = kc / 14;
        int hf = lane >> 5, n = lane & 31;
        int kd = 0, kh = 0, kw = 0; bool valid = true;
        if (c < 9)        { kd = hf ? 1 : -1; kh = c / 3 - 1; kw = c % 3 - 1; }
        else if (c < 12)  { kd = 0; kh = hf ? 1 : -1; kw = (c - 9) - 1; }
        else if (c == 12) { kd = 0; kh = 0; kw = hf ? 1 : -1; }
        else              { valid = (hf == 0); }
        float val = 0.f;
        if (valid) {
            int tap = (kd + 1) * 9 + (kh + 1) * 3 + (kw + 1);
            const float* wsel = (k == 0) ? w_s : (k == 1) ? w_m : w_l;
            #pragma unroll
            for (int g = 0; g < 8; ++g)
                val += w_final[n * 8 + g] * wsel[(g * 8 + j) * 27 + tap];
        }
        bpack[i] = (_Float16)val;
    } else if (i < 21504 + 18720) {
        int j = i - 21504;
        int oc = j & 31; int it = j >> 5; int ic = it / 9; int t = it - ic * 9;
        wp1T[j] = w_pred1[(oc * 65 + ic) * 9 + t];
    }
}

// ---------------------------------------------------------------------------
// Kernel 2 (norm fused in, R4 — proven ~48 µs win): correlation volume ->
//  padded f16 volume. Block = (32 w) x (8 g) at one (h,b). Stages the
//  80-column feat_r window [w0-48, w0+32) into LDS, L2-normalizing each
//  (g,w) 8-vector on the fly (1/sqrt(8) folded in). Own fl vector normalized
//  in registers. LDS stride 68 staggers banks.
// ---------------------------------------------------------------------------
__global__ __launch_bounds__(256) void corr_kernel(const float* __restrict__ feat_l,
                                                   const float* __restrict__ feat_r,
                                                   _Float16* __restrict__ baseh) {
    __shared__ float frl[80 * 68];   // 21,760 B
    int tid = threadIdx.x;
    int h = blockIdx.y;
    int b = blockIdx.z;
    int w0 = blockIdx.x * 32;
    int wbase = w0 - 48;             // LDS window start (may be < 0)

    // stage + normalize feat_r window: 8 g x 80 iw pairs
    for (int p = tid; p < 640; p += 256) {
        int gg = p / 80;
        int iw = p - gg * 80;
        int wg = wbase + iw;
        if (wg >= 0) {
            const float* src = feat_r + (size_t)(b * 64 + gg * 8) * HW_ + h * W_ + wg;
            float v[8]; float s = 0.f;
            #pragma unroll
            for (int c = 0; c < 8; ++c) { v[c] = src[(size_t)c * HW_]; s += v[c] * v[c]; }
            float inv = 0.35355339059327373f / fmaxf(sqrtf(s), 1e-12f);  // incl 1/sqrt(8)
            #pragma unroll
            for (int c = 0; c < 8; ++c) frl[iw * 68 + gg * 8 + c] = v[c] * inv;
        }
    }

    // own fl vector, normalized (no 1/sqrt(8) here)
    int g = tid & 7, wi = tid >> 3;
    int w = w0 + wi;
    const float* fls = feat_l + (size_t)(b * 64 + g * 8) * HW_ + h * W_ + w;
    float a[8]; float s = 0.f;
    #pragma unroll
    for (int c = 0; c < 8; ++c) { a[c] = fls[(size_t)c * HW_]; s += a[c] * a[c]; }
    float inv = 1.0f / fmaxf(sqrtf(s), 1e-12f);
    #pragma unroll
    for (int c = 0; c < 8; ++c) a[c] *= inv;

    __syncthreads();

    _Float16* dst = baseh + (size_t)((b * DP_ + 4) * HP_ + 4 + h) * WP_ * 8 + (size_t)(4 + w) * 8 + g;
    for (int d = 0; d < D_; ++d) {
        int wd = w - d;
        float acc = 0.f;
        if (wd >= 0) {
            const float* fr = frl + (wd - wbase) * 68 + g * 8;
            acc = a[0]*fr[0] + a[1]*fr[1] + a[2]*fr[2] + a[3]*fr[3]
                + a[4]*fr[4] + a[5]*fr[5] + a[6]*fr[6] + a[7]*fr[7];
        }
        dst[(size_t)d * PLANE_] = (_Float16)acc;
    }
}

// ---------------------------------------------------------------------------
// Kernel 3: 2D conv(65->32,3x3)+BN+relu+1x1(32->3)+softmax -> 3 planes swp[k]
// ---------------------------------------------------------------------------
__global__ __launch_bounds__(256) void pred_kernel(const float* __restrict__ feat_l,
                                                   const float* __restrict__ edge,
                                                   const float* __restrict__ wp1T,
                                                   const float* __restrict__ gamma,
                                                   const float* __restrict__ beta,
                                                   const float* __restrict__ mean,
                                                   const float* __restrict__ var,
                                                   const float* __restrict__ w2,
                                                   const float* __restrict__ b2,
                                                   const float* __restrict__ temp,
                                                   float* __restrict__ swp) {
    int pid = blockIdx.x * 256 + threadIdx.x;   // 0..36863
    int b = pid / HW_; int hw = pid - b * HW_;
    int h = hw / W_;   int w = hw - h * W_;

    float acc[32];
    #pragma unroll
    for (int i = 0; i < 32; ++i) acc[i] = 0.f;

    for (int ic = 0; ic < 65; ++ic) {
        const float* src = (ic < 64) ? (feat_l + (size_t)(b * 64 + ic) * HW_)
                                     : (edge + (size_t)b * HW_);
        float v[9];
        #pragma unroll
        for (int ky = 0; ky < 3; ++ky) {
            int y = h + ky - 1;
            #pragma unroll
            for (int kx = 0; kx < 3; ++kx) {
                int x = w + kx - 1;
                bool ok = (y >= 0) && (y < H_) && (x < W_) && (x >= 0);
                v[ky * 3 + kx] = ok ? src[y * W_ + x] : 0.f;
            }
        }
        #pragma unroll
        for (int t = 0; t < 9; ++t) {
            const float* wrow = wp1T + (ic * 9 + t) * 32;
            float vv = v[t];
            #pragma unroll
            for (int oc = 0; oc < 32; ++oc) acc[oc] = fmaf(vv, wrow[oc], acc[oc]);
        }
    }

    float l0 = b2[0], l1 = b2[1], l2 = b2[2];
    #pragma unroll
    for (int oc = 0; oc < 32; ++oc) {
        float sc = gamma[oc] / sqrtf(var[oc] + 1e-5f);
        float xb = (acc[oc] - mean[oc]) * sc + beta[oc];
        float r = fmaxf(xb, 0.f);
        l0 = fmaf(w2[0 * 32 + oc], r, l0);
        l1 = fmaf(w2[1 * 32 + oc], r, l1);
        l2 = fmaf(w2[2 * 32 + oc], r, l2);
    }
    float t = fmaxf(temp[0], 0.1f);
    float it = 1.0f / t;
    l0 *= it; l1 *= it; l2 *= it;
    float m = fmaxf(l0, fmaxf(l1, l2));
    float e0 = __expf(l0 - m), e1 = __expf(l1 - m), e2 = __expf(l2 - m);
    float is = 1.0f / (e0 + e1 + e2);
    swp[0 * (B_ * HW_) + pid] = e0 * is;
    swp[1 * (B_ * HW_) + pid] = e1 * is;
    swp[2 * (B_ * HW_) + pid] = e2 * is;
}

// ---------------------------------------------------------------------------
// Kernel 4: MFMA 32x32x16 fused conv — EXACT R3 configuration (fastest
//  measured: <151 µs). 256 threads = 4 waves = (2 h) x (2 d-chunks),
//  grid (6,48,B*2), chunk-144 XCD swizzle, LDS-B (43 KB), launch_bounds(256,2).
//  R4 lesson: 512-thread blocks made the compiler pick a 40-VGPR minimal
//  schedule (few loads in flight) -> 187 µs despite 40% occupancy. This
//  256-thread shape is where codegen batches ~25 loads (VGPR ~120). Do not
//  change block shape or launch_bounds without checking VGPR_Count.
//  D: col = lane&31 = o, row = (reg&3)+8*(reg>>2)+4*hf = w-offset.
// ---------------------------------------------------------------------------
__global__ __launch_bounds__(256, 2) void fusedconv_mfma32(
        const _Float16* __restrict__ baseh,
        const float* __restrict__ swp,
        const _Float16* __restrict__ bpack,
        const float* __restrict__ bf,
        float* __restrict__ out) {
    __shared__ _Float16 bsh[3 * 14 * 64 * 8];   // 43,008 B

    int tid = threadIdx.x;
    // stage bpack -> LDS (2688 f16x8 chunks)
    {
        const f16x8* srcv = (const f16x8*)bpack;
        f16x8* dstv = (f16x8*)bsh;
        for (int i = tid; i < 2688; i += 256) dstv[i] = srcv[i];
    }

    // XCD-aware bijective swizzle of the linear block id (nwg = 1152 = 8*144)
    int L   = blockIdx.x + 6 * (blockIdx.y + 48 * blockIdx.z);
    int sL  = (L & 7) * 144 + (L >> 3);
    int bx  = sL % 6;
    int byz = sL / 6;
    int by  = byz % 48;
    int bz  = byz / 48;

    int wave = tid >> 6, lane = tid & 63;
    int m = lane & 31, hf = lane >> 5;
    int hh = wave >> 1, dh = wave & 1;
    int w0 = bx * 32;
    int h  = by * 2 + hh;
    int b  = bz >> 1;
    int dq = bz & 1;
    int d0 = dq * 24 + dh * 12;

    // softmax weights as f16 splats (per-lane row m)
    f16x8 swh[3];
    #pragma unroll
    for (int k = 0; k < 3; ++k) {
        float s = swp[k * (B_ * HW_) + b * HW_ + h * W_ + w0 + m];
        _Float16 hs = (_Float16)s;
        f16x8 t;
        #pragma unroll
        for (int j = 0; j < 8; ++j) t[j] = hs;
        swh[k] = t;
    }

    // half-wave address deltas per (scale, class), bytes
    int hdv[3][4];
    #pragma unroll
    for (int k = 0; k < 3; ++k) {
        int dil = 1 << k;
        hdv[k][0] = hf * (2 * dil * HP_ * WP_ * 8 * 2);
        hdv[k][1] = hf * (2 * dil * WP_ * 8 * 2);
        hdv[k][2] = hf * (2 * dil * 8 * 2);
        hdv[k][3] = 0;
    }

    const char* bb = (const char*)baseh;
    char*       ob = (char*)out;

    // byte offset of interior origin (d0-plane, h, w0+m)
    unsigned pm = (unsigned)(((((b * DP_ + 4 + d0) * HP_ + 4 + h) * WP_ + 4 + w0 + m) * 8) * 2);
    float bias = bf[m];   // o = lane&31
    unsigned outoff = (unsigned)((((b * OUT_ + m) * D_ + d0) * HW_ + h * W_ + w0 + 4 * hf) * 4);

    __syncthreads();

    for (int d = 0; d < 12; ++d) {
        // opaque per-iteration LDS byte offset (value lane*16): defeats LICM/hoist
        unsigned bofs = (unsigned)(lane * 16);
        asm volatile("" : "+v"(bofs));
        const char* bshp = (const char*)bsh + bofs;

        f32x16 acc0, acc1;
        #pragma unroll
        for (int i = 0; i < 16; ++i) { acc0[i] = 0.f; acc1[i] = 0.f; }
        #pragma unroll
        for (int k = 0; k < 3; ++k) {
            int dil = 1 << k;
            #pragma unroll
            for (int c = 0; c < 14; ++c) {
                int coff, cls;
                if (c < 9)        { coff = ((-dil * HP_ + (c / 3 - 1) * dil) * WP_ * 8 + (c % 3 - 1) * dil * 8) * 2; cls = 0; }
                else if (c < 12)  { coff = ((-dil) * WP_ * 8 + ((c - 9) - 1) * dil * 8) * 2;                          cls = 1; }
                else if (c == 12) { coff = -dil * 16;                                                                  cls = 2; }
                else              { coff = 0;                                                                          cls = 3; }
                unsigned a = pm + (unsigned)(hdv[k][cls] + coff);
                f16x8 av = *(const f16x8*)(bb + a);
                f16x8 Bv = *(const f16x8*)(bshp + (k * 14 + c) * 1024);
                av = av * swh[k];
                if (c & 1) acc1 = __builtin_amdgcn_mfma_f32_32x32x16_f16(av, Bv, acc1, 0, 0, 0);
                else       acc0 = __builtin_amdgcn_mfma_f32_32x32x16_f16(av, Bv, acc0, 0, 0, 0);
            }
        }
        #pragma unroll
        for (int q = 0; q < 4; ++q) {
            f32x4 v;
            #pragma unroll
            for (int i = 0; i < 4; ++i) v[i] = acc0[4 * q + i] + acc1[4 * q + i] + bias;
            *(f32x4*)(ob + outoff + q * 32) = v;   // rows 8q+4hf..+3, o = m
        }
        pm += PLANE_ * 2;
        outoff += HW_ * 4;
    }
}

// ---------------------------------------------------------------------------
extern "C" void kernel_launch(void* const* d_in, const int* in_sizes, int n_in,
                              void* d_out, int out_size, void* d_ws, size_t ws_size,
                              hipStream_t stream) {
    const float* feat_l   = (const float*)d_in[0];
    const float* feat_r   = (const float*)d_in[1];
    const float* edge     = (const float*)d_in[2];
    const float* w_pred1  = (const float*)d_in[3];
    const float* bn_gamma = (const float*)d_in[4];
    const float* bn_beta  = (const float*)d_in[5];
    const float* bn_mean  = (const float*)d_in[6];
    const float* bn_var   = (const float*)d_in[7];
    const float* w_pred2  = (const float*)d_in[8];
    const float* b_pred2  = (const float*)d_in[9];
    const float* temp     = (const float*)d_in[10];
    const float* w_s      = (const float*)d_in[11];
    const float* w_m      = (const float*)d_in[12];
    const float* w_l      = (const float*)d_in[13];
    const float* w_final  = (const float*)d_in[14];
    const float* b_final  = (const float*)d_in[15];
    float* out = (float*)d_out;

    float* ws = (float*)d_ws;
    _Float16*  baseh = (_Float16*)(ws + OFF_BASEH);
    float*     swp   = ws + OFF_SW;
    _Float16*  bpack = (_Float16*)(ws + OFF_BPACK);
    float*     wp1T  = ws + OFF_WP1T;

    // 0: weight prep
    wtrans_kernel<<<dim3(158), 256, 0, stream>>>(w_s, w_m, w_l, w_final, w_pred1, bpack, wp1T);
    // zero the padded volume (halo must be 0; ws is poisoned each launch)
    hipMemsetAsync(baseh, 0, (size_t)BASEH_HALFS * sizeof(_Float16), stream);
    // 2: correlation volume -> padded f16 (norm fused in)
    corr_kernel<<<dim3(W_ / 32, H_, B_), 256, 0, stream>>>(feat_l, feat_r, baseh);
    // 3: pred path -> softmax planes
    pred_kernel<<<dim3(B_ * HW_ / 256), 256, 0, stream>>>(feat_l, edge, wp1T, bn_gamma,
                                                          bn_beta, bn_mean, bn_var,
                                                          w_pred2, b_pred2, temp, swp);
    // 4: MFMA 32x32 fused conv (R3 config: 256-thread blocks, LDS-B, swizzle)
    fusedconv_mfma32<<<dim3(W_ / 32, H_ / 2, B_ * 2), 256, 0, stream>>>(baseh, swp, bpack, b_final, out);
}